// Round 1
// baseline (837.758 us; speedup 1.0000x reference)
//
#include <hip/hip_runtime.h>
#include <hip/hip_bf16.h>

typedef __attribute__((ext_vector_type(4))) float f32x4;
typedef __attribute__((ext_vector_type(8))) short short8;
typedef __attribute__((ext_vector_type(4))) unsigned short us4;
typedef __attribute__((ext_vector_type(2))) unsigned short us2;
typedef unsigned short u16;

__device__ __forceinline__ float bf2f(u16 u) {
  unsigned int x = ((unsigned int)u) << 16;
  float f; __builtin_memcpy(&f, &x, 4); return f;
}
__device__ __forceinline__ u16 f2bf(float f) {
  __hip_bfloat16 h = __float2bfloat16(f);
  u16 u; __builtin_memcpy(&u, &h, 2); return u;
}

// async global->LDS, 16B per lane. LDS dest must be (wave-uniform base + lane*16),
// which our staging index pattern guarantees.
#define GLL16(g, l) __builtin_amdgcn_global_load_lds( \
    (const __attribute__((address_space(1))) unsigned int*)(g), \
    (__attribute__((address_space(3))) unsigned int*)(l), 16, 0, 0)

#define MFMA16x32(a, b, c) __builtin_amdgcn_mfma_f32_16x16x32_bf16(a, b, c, 0, 0, 0)

// ---------------- conversion kernels ----------------

// x1,x2 f32 -> xc bf16 [B*S][D], row m = b*2048 + n; n<1024 from x1 else x2
__global__ __launch_bounds__(256) void k_convert_x(const float* __restrict__ x1,
                                                   const float* __restrict__ x2,
                                                   u16* __restrict__ xc) {
  int tid = blockIdx.x * 256 + threadIdx.x;   // 1,048,576 threads, 8 elems each
  int e = tid * 8;
  int m = e >> 11, d = e & 2047;
  int b = m >> 11, n = m & 2047;
  const float* src = (n < 1024) ? (x1 + ((b << 10) + n) * 2048 + d)
                                : (x2 + ((b << 10) + n - 1024) * 2048 + d);
  float4 v0 = *(const float4*)src;
  float4 v1 = *(const float4*)(src + 4);
  us4 a = {f2bf(v0.x), f2bf(v0.y), f2bf(v0.z), f2bf(v0.w)};
  us4 c = {f2bf(v1.x), f2bf(v1.y), f2bf(v1.z), f2bf(v1.w)};
  *(us4*)(xc + e) = a;
  *(us4*)(xc + e + 4) = c;
}

struct W8 { const float* w[8]; };

// W f32 [K=2048][N=2048] -> Wt bf16 [N][K]   (64x64 tiles via LDS)
__global__ __launch_bounds__(256) void k_wt(W8 p, u16* __restrict__ wtbase) {
  __shared__ u16 lt[64][72];
  const float* W = p.w[blockIdx.z];
  u16* Wt = wtbase + (size_t)blockIdx.z * 4194304u;
  int k0 = blockIdx.x * 64, n0 = blockIdx.y * 64;
  int t = threadIdx.x;
#pragma unroll
  for (int i = 0; i < 4; ++i) {
    int lin = t + i * 256;          // chunk of 4 f32
    int r = lin >> 4, c4 = (lin & 15) * 4;
    float4 v = *(const float4*)&W[(k0 + r) * 2048 + n0 + c4];
    us4 u = {f2bf(v.x), f2bf(v.y), f2bf(v.z), f2bf(v.w)};
    *(us4*)&lt[r][c4] = u;
  }
  __syncthreads();
#pragma unroll
  for (int i = 0; i < 8; ++i) {
    int lin = t + i * 256;
    int rd = lin >> 5, cs = (lin & 31) * 2;
    us2 u = {lt[cs][rd], lt[cs + 1][rd]};
    *(us2*)&Wt[(n0 + rd) * 2048 + k0 + cs] = u;
  }
}

// V bf16 [B,S,D] -> Vt bf16 [B,D,S]
__global__ __launch_bounds__(256) void k_vt(const u16* __restrict__ V, u16* __restrict__ Vt) {
  __shared__ u16 lt[64][72];
  int b = blockIdx.z;
  int s0 = blockIdx.x * 64, d0 = blockIdx.y * 64;
  int t = threadIdx.x;
#pragma unroll
  for (int i = 0; i < 2; ++i) {
    int lin = t + i * 256;          // chunk of 8
    int r = lin >> 3, c8 = (lin & 7) * 8;
    short8 v = *(const short8*)&V[(b * 2048 + s0 + r) * 2048 + d0 + c8];
    *(short8*)&lt[r][c8] = v;
  }
  __syncthreads();
#pragma unroll
  for (int i = 0; i < 8; ++i) {
    int lin = t + i * 256;
    int rd = lin >> 5, cs = (lin & 31) * 2;
    us2 u = {lt[cs][rd], lt[cs + 1][rd]};
    *(us2*)&Vt[(b * 2048 + d0 + rd) * 2048 + s0 + cs] = u;
  }
}

// RoPE in place on Q (with 1/sqrt(128) scale) and K; interleaved-pair rotation
__global__ __launch_bounds__(256) void k_rope(u16* __restrict__ Qb, u16* __restrict__ Kb,
                                              const float* __restrict__ cos1,
                                              const float* __restrict__ sin1,
                                              const float* __restrict__ cos2,
                                              const float* __restrict__ sin2) {
  u16* T = blockIdx.y ? Kb : Qb;
  const float scale = blockIdx.y ? 1.f : 0.08838834764831843f;
  int tid = blockIdx.x * 256 + threadIdx.x;
  int e = tid * 8;
  int m = e >> 11;
  int n = m & 2047;
  int dh0 = e & 127;
  const float* cr; const float* sr;
  if (n < 1024) { cr = cos1 + n * 128; sr = sin1 + n * 128; }
  else          { cr = cos2 + (n - 1024) * 128; sr = sin2 + (n - 1024) * 128; }
  float4 c0 = *(const float4*)(cr + dh0), c1 = *(const float4*)(cr + dh0 + 4);
  float4 s0 = *(const float4*)(sr + dh0), s1 = *(const float4*)(sr + dh0 + 4);
  short8 xv = *(short8*)(T + e);
  float x0 = bf2f((u16)xv[0]), x1 = bf2f((u16)xv[1]), x2 = bf2f((u16)xv[2]), x3 = bf2f((u16)xv[3]);
  float x4 = bf2f((u16)xv[4]), x5 = bf2f((u16)xv[5]), x6 = bf2f((u16)xv[6]), x7 = bf2f((u16)xv[7]);
  us4 o0 = { f2bf((x0 * c0.x - x1 * s0.x) * scale), f2bf((x1 * c0.x + x0 * s0.x) * scale),
             f2bf((x2 * c0.z - x3 * s0.z) * scale), f2bf((x3 * c0.z + x2 * s0.z) * scale) };
  us4 o1 = { f2bf((x4 * c1.x - x5 * s1.x) * scale), f2bf((x5 * c1.x + x4 * s1.x) * scale),
             f2bf((x6 * c1.z - x7 * s1.z) * scale), f2bf((x7 * c1.z + x6 * s1.z) * scale) };
  *(us4*)(T + e) = o0;
  *(us4*)(T + e + 4) = o1;
}

// ---------------- GEMM core (m97-style, 128x128, BK=64, 4 waves) ----------------

__device__ __forceinline__ void gemm_core(const u16* __restrict__ A,
                                          const u16* __restrict__ Bt,
                                          u16* lA, u16* lB,
                                          f32x4 acc[4][4], int m0, int n0) {
  const int t = threadIdx.x;
  const int lane = t & 63;
  const int lq = lane & 15, lg = lane >> 4;
  const int wr = (t >> 7) & 1, wc = (t >> 6) & 1;
  for (int k0 = 0; k0 < 2048; k0 += 64) {
    __syncthreads();
#pragma unroll
    for (int i = 0; i < 4; ++i) {
      int chunk = i * 256 + t;            // [0,1024): r = chunk/8, c16 = chunk%8
      int r = chunk >> 3, c = chunk & 7;
      GLL16(A + ((m0 + r) * 2048 + k0 + c * 8), lA + chunk * 8);
      GLL16(Bt + ((n0 + r) * 2048 + k0 + c * 8), lB + chunk * 8);
    }
    asm volatile("s_waitcnt vmcnt(0)" ::: "memory");
    __syncthreads();
#pragma unroll
    for (int kc = 0; kc < 2; ++kc) {
      short8 af[4], bf[4];
#pragma unroll
      for (int rf = 0; rf < 4; ++rf)
        af[rf] = *(const short8*)(lA + (wr * 64 + rf * 16 + lq) * 64 + kc * 32 + lg * 8);
#pragma unroll
      for (int cf = 0; cf < 4; ++cf)
        bf[cf] = *(const short8*)(lB + (wc * 64 + cf * 16 + lq) * 64 + kc * 32 + lg * 8);
#pragma unroll
      for (int rf = 0; rf < 4; ++rf)
#pragma unroll
        for (int cf = 0; cf < 4; ++cf)
          acc[rf][cf] = MFMA16x32(af[rf], bf[cf], acc[rf][cf]);
    }
  }
}

struct QKVP {
  const u16* wt[6];      // [type*2 + stream]: q1,q2,k1,k2,v1,v2
  const float* bias[6];
  u16* out[3];           // Q, K, V  (bf16 [B,S,D])
  const u16* xc;
};

__global__ __launch_bounds__(256) void k_gemm_qkv(QKVP p) {
  __shared__ u16 lA[128 * 64];
  __shared__ u16 lB[128 * 64];
  const int m0 = blockIdx.x * 128, n0 = blockIdx.y * 128;
  const int idx = blockIdx.z * 2 + ((m0 >> 10) & 1);
  f32x4 acc[4][4];
  const f32x4 z4 = {0.f, 0.f, 0.f, 0.f};
#pragma unroll
  for (int a = 0; a < 4; ++a)
#pragma unroll
    for (int b = 0; b < 4; ++b) acc[a][b] = z4;
  gemm_core(p.xc, p.wt[idx], lA, lB, acc, m0, n0);
  const float* bias = p.bias[idx];
  u16* out = p.out[blockIdx.z];
  const int lane = threadIdx.x & 63, lq = lane & 15, lg = lane >> 4;
  const int wr = (threadIdx.x >> 7) & 1, wc = (threadIdx.x >> 6) & 1;
#pragma unroll
  for (int cf = 0; cf < 4; ++cf) {
    int col = n0 + wc * 64 + cf * 16 + lq;
    float bv = bias[col];
#pragma unroll
    for (int rf = 0; rf < 4; ++rf) {
      int row0 = m0 + wr * 64 + rf * 16 + lg * 4;
#pragma unroll
      for (int j = 0; j < 4; ++j)
        out[(row0 + j) * 2048 + col] = f2bf(acc[rf][cf][j] + bv);
    }
  }
}

__global__ __launch_bounds__(256) void k_gemm_out(const u16* __restrict__ O,
                                                  const u16* __restrict__ wt0,
                                                  const u16* __restrict__ wt1,
                                                  const float* __restrict__ b0,
                                                  const float* __restrict__ b1,
                                                  float* __restrict__ out) {
  __shared__ u16 lA[128 * 64];
  __shared__ u16 lB[128 * 64];
  const int m0 = blockIdx.x * 128, n0 = blockIdx.y * 128;
  const int stream1 = (m0 >> 10) & 1;
  f32x4 acc[4][4];
  const f32x4 z4 = {0.f, 0.f, 0.f, 0.f};
#pragma unroll
  for (int a = 0; a < 4; ++a)
#pragma unroll
    for (int b = 0; b < 4; ++b) acc[a][b] = z4;
  gemm_core(O, stream1 ? wt1 : wt0, lA, lB, acc, m0, n0);
  const float* bias = stream1 ? b1 : b0;
  const int lane = threadIdx.x & 63, lq = lane & 15, lg = lane >> 4;
  const int wr = (threadIdx.x >> 7) & 1, wc = (threadIdx.x >> 6) & 1;
#pragma unroll
  for (int cf = 0; cf < 4; ++cf) {
    int col = n0 + wc * 64 + cf * 16 + lq;
    float bv = bias[col];
#pragma unroll
    for (int rf = 0; rf < 4; ++rf) {
      int row0 = m0 + wr * 64 + rf * 16 + lg * 4;
#pragma unroll
      for (int j = 0; j < 4; ++j) {
        int row = row0 + j;
        int b = row >> 11, n = row & 2047;
        float* dst = stream1 ? out + 4194304 + (((b << 10) + n - 1024) * 2048 + col)
                             : out + (((b << 10) + n) * 2048 + col);
        *dst = acc[rf][cf][j] + bv;
      }
    }
  }
}

// ---------------- flash attention (swapped-operand, per-wave 16 q-rows) ----------------
// Q,K bf16 [B,S,D] (RoPE'd, Q pre-scaled); Vt bf16 [B,D,S]; O bf16 [B,S,D]
__global__ __launch_bounds__(256) void k_attn(const u16* __restrict__ Q,
                                              const u16* __restrict__ K,
                                              const u16* __restrict__ Vt,
                                              u16* __restrict__ O) {
  __shared__ u16 pl[4 * 16 * 32];          // per-wave P tile [16 q][32 k]
  const int t = threadIdx.x, lane = t & 63, w = t >> 6;
  const int lq = lane & 15, g = lane >> 4;
  const int bh = blockIdx.y, b = bh >> 4, h = bh & 15;
  const int qrow = blockIdx.x * 64 + w * 16 + lq;
  const u16* Qp = Q + (b * 2048 + qrow) * 2048 + h * 128 + g * 8;
  short8 qf[4];
#pragma unroll
  for (int c = 0; c < 4; ++c) qf[c] = *(const short8*)(Qp + c * 32);
  f32x4 oacc[8];
  const f32x4 z4 = {0.f, 0.f, 0.f, 0.f};
#pragma unroll
  for (int dc = 0; dc < 8; ++dc) oacc[dc] = z4;
  float m_run = -1e30f, l_run = 0.f;
  const u16* Kb = K + (b * 2048) * 2048 + h * 128 + g * 8;
  const u16* Vb = Vt + (b * 2048 + h * 128 + lq) * 2048 + g * 8;
  u16* plw = pl + w * 512 + lq * 32;
  for (int kt = 0; kt < 2048; kt += 32) {
    f32x4 s0 = z4, s1 = z4;
    const u16* kp0 = Kb + (kt + lq) * 2048;
#pragma unroll
    for (int c = 0; c < 4; ++c) {
      short8 kf0 = *(const short8*)(kp0 + c * 32);
      short8 kf1 = *(const short8*)(kp0 + 16 * 2048 + c * 32);
      s0 = MFMA16x32(kf0, qf[c], s0);   // S^T: lane holds q=lq, keys kt+g*4+j
      s1 = MFMA16x32(kf1, qf[c], s1);   // keys kt+16+g*4+j
    }
    float pm = fmaxf(fmaxf(fmaxf(s0[0], s0[1]), fmaxf(s0[2], s0[3])),
                     fmaxf(fmaxf(s1[0], s1[1]), fmaxf(s1[2], s1[3])));
    pm = fmaxf(pm, __shfl_xor(pm, 16));
    pm = fmaxf(pm, __shfl_xor(pm, 32));
    const float mnew = fmaxf(m_run, pm);
    const float r = __expf(m_run - mnew);
    float p0[4], p1[4];
    float ps = 0.f;
#pragma unroll
    for (int j = 0; j < 4; ++j) { p0[j] = __expf(s0[j] - mnew); ps += p0[j]; }
#pragma unroll
    for (int j = 0; j < 4; ++j) { p1[j] = __expf(s1[j] - mnew); ps += p1[j]; }
    ps += __shfl_xor(ps, 16);
    ps += __shfl_xor(ps, 32);
    l_run = l_run * r + ps;
    m_run = mnew;
#pragma unroll
    for (int dc = 0; dc < 8; ++dc) oacc[dc] = oacc[dc] * r;
    us4 w0 = {f2bf(p0[0]), f2bf(p0[1]), f2bf(p0[2]), f2bf(p0[3])};
    us4 w1 = {f2bf(p1[0]), f2bf(p1[1]), f2bf(p1[2]), f2bf(p1[3])};
    *(us4*)(plw + g * 4) = w0;
    *(us4*)(plw + 16 + g * 4) = w1;
    short8 pb = *(const short8*)(plw + g * 8);   // P^T B-operand: q=lq, keys g*8..+7
#pragma unroll
    for (int dc = 0; dc < 8; ++dc) {
      short8 vf = *(const short8*)(Vb + dc * 16 * 2048 + kt);
      oacc[dc] = MFMA16x32(vf, pb, oacc[dc]);    // O^T: lane holds q=lq, dh=dc*16+g*4+j
    }
  }
  const float inv = 1.f / l_run;
  u16* Op = O + (b * 2048 + qrow) * 2048 + h * 128 + g * 4;
#pragma unroll
  for (int dc = 0; dc < 8; ++dc) {
    us4 ov = {f2bf(oacc[dc][0] * inv), f2bf(oacc[dc][1] * inv),
              f2bf(oacc[dc][2] * inv), f2bf(oacc[dc][3] * inv)};
    *(us4*)(Op + dc * 16) = ov;
  }
}

// ---------------- host ----------------

extern "C" void kernel_launch(void* const* d_in, const int* in_sizes, int n_in,
                              void* d_out, int out_size, void* d_ws, size_t ws_size,
                              hipStream_t stream) {
  const float* x1   = (const float*)d_in[0];
  const float* x2   = (const float*)d_in[1];
  const float* cos1 = (const float*)d_in[2];
  const float* sin1 = (const float*)d_in[3];
  const float* cos2 = (const float*)d_in[4];
  const float* sin2 = (const float*)d_in[5];
  W8 wp; const float* bias[8];
  for (int i = 0; i < 8; ++i) {
    wp.w[i] = (const float*)d_in[6 + 2 * i];   // wq1,wk1,wv1,wo1,wq2,wk2,wv2,wo2
    bias[i] = (const float*)d_in[7 + 2 * i];   // bq1,bk1,bv1,bo1,bq2,bk2,bv2,bo2
  }
  float* out = (float*)d_out;
  u16* ws = (u16*)d_ws;
  const size_t NX = 8388608;    // B*S*D
  const size_t WSZ = 4194304;   // 2048*2048
  u16* xc = ws;                 // also reused as Vt after QKV GEMM
  u16* wt = ws + NX;
  u16* Qb = wt + 8 * WSZ;
  u16* Kb = Qb + NX;
  u16* Vb = Kb + NX;
  u16* Ob = Vb + NX;
  u16* Vt = xc;
  if (ws_size < (size_t)((Ob + NX) - ws) * sizeof(u16)) return;  // ~151 MB needed

  k_convert_x<<<dim3(4096), dim3(256), 0, stream>>>(x1, x2, xc);
  k_wt<<<dim3(32, 32, 8), dim3(256), 0, stream>>>(wp, wt);

  QKVP qp;
  qp.wt[0] = wt + 0 * WSZ; qp.wt[1] = wt + 4 * WSZ;   // wq1, wq2
  qp.wt[2] = wt + 1 * WSZ; qp.wt[3] = wt + 5 * WSZ;   // wk1, wk2
  qp.wt[4] = wt + 2 * WSZ; qp.wt[5] = wt + 6 * WSZ;   // wv1, wv2
  qp.bias[0] = bias[0]; qp.bias[1] = bias[4];
  qp.bias[2] = bias[1]; qp.bias[3] = bias[5];
  qp.bias[4] = bias[2]; qp.bias[5] = bias[6];
  qp.out[0] = Qb; qp.out[1] = Kb; qp.out[2] = Vb;
  qp.xc = xc;
  k_gemm_qkv<<<dim3(32, 16, 3), dim3(256), 0, stream>>>(qp);

  k_rope<<<dim3(4096, 2), dim3(256), 0, stream>>>(Qb, Kb, cos1, sin1, cos2, sin2);
  k_vt<<<dim3(32, 32, 2), dim3(256), 0, stream>>>(Vb, Vt);
  k_attn<<<dim3(32, 32), dim3(256), 0, stream>>>(Qb, Kb, Vt, Ob);
  k_gemm_out<<<dim3(32, 16), dim3(256), 0, stream>>>(Ob, wt + 3 * WSZ, wt + 7 * WSZ,
                                                     bias[3], bias[7], out);
}

// Round 2
// 391.623 us; speedup vs baseline: 2.1392x; 2.1392x over previous
//
#include <hip/hip_runtime.h>
#include <hip/hip_bf16.h>

typedef __attribute__((ext_vector_type(4))) float f32x4;
typedef __attribute__((ext_vector_type(8))) short short8;
typedef __attribute__((ext_vector_type(4))) unsigned short us4;
typedef __attribute__((ext_vector_type(2))) unsigned short us2;
typedef unsigned short u16;

__device__ __forceinline__ float bf2f(u16 u) {
  unsigned int x = ((unsigned int)u) << 16;
  float f; __builtin_memcpy(&f, &x, 4); return f;
}
__device__ __forceinline__ u16 f2bf(float f) {
  __hip_bfloat16 h = __float2bfloat16(f);
  u16 u; __builtin_memcpy(&u, &h, 2); return u;
}

// async global->LDS, 16B per lane. LDS dest must be (wave-uniform base + lane*16),
// which our staging index pattern guarantees.
#define GLL16(g, l) __builtin_amdgcn_global_load_lds( \
    (const __attribute__((address_space(1))) unsigned int*)(g), \
    (__attribute__((address_space(3))) unsigned int*)(l), 16, 0, 0)

#define MFMA16x32(a, b, c) __builtin_amdgcn_mfma_f32_16x16x32_bf16(a, b, c, 0, 0, 0)

// ---------------- conversion kernels ----------------

// x1,x2 f32 -> xc bf16 [B*S][D], row m = b*2048 + n; n<1024 from x1 else x2
__global__ __launch_bounds__(256) void k_convert_x(const float* __restrict__ x1,
                                                   const float* __restrict__ x2,
                                                   u16* __restrict__ xc) {
  int tid = blockIdx.x * 256 + threadIdx.x;   // 1,048,576 threads, 8 elems each
  int e = tid * 8;
  int m = e >> 11, d = e & 2047;
  int b = m >> 11, n = m & 2047;
  const float* src = (n < 1024) ? (x1 + ((b << 10) + n) * 2048 + d)
                                : (x2 + ((b << 10) + n - 1024) * 2048 + d);
  float4 v0 = *(const float4*)src;
  float4 v1 = *(const float4*)(src + 4);
  us4 a = {f2bf(v0.x), f2bf(v0.y), f2bf(v0.z), f2bf(v0.w)};
  us4 c = {f2bf(v1.x), f2bf(v1.y), f2bf(v1.z), f2bf(v1.w)};
  *(us4*)(xc + e) = a;
  *(us4*)(xc + e + 4) = c;
}

struct W8 { const float* w[8]; };

// W f32 [K=2048][N=2048] -> Wt bf16 [N][K]   (64x64 tiles via LDS)
__global__ __launch_bounds__(256) void k_wt(W8 p, u16* __restrict__ wtbase) {
  __shared__ u16 lt[64][72];
  const float* W = p.w[blockIdx.z];
  u16* Wt = wtbase + (size_t)blockIdx.z * 4194304u;
  int k0 = blockIdx.x * 64, n0 = blockIdx.y * 64;
  int t = threadIdx.x;
#pragma unroll
  for (int i = 0; i < 4; ++i) {
    int lin = t + i * 256;          // chunk of 4 f32
    int r = lin >> 4, c4 = (lin & 15) * 4;
    float4 v = *(const float4*)&W[(k0 + r) * 2048 + n0 + c4];
    us4 u = {f2bf(v.x), f2bf(v.y), f2bf(v.z), f2bf(v.w)};
    *(us4*)&lt[r][c4] = u;
  }
  __syncthreads();
#pragma unroll
  for (int i = 0; i < 8; ++i) {
    int lin = t + i * 256;
    int rd = lin >> 5, cs = (lin & 31) * 2;
    us2 u = {lt[cs][rd], lt[cs + 1][rd]};
    *(us2*)&Wt[(n0 + rd) * 2048 + k0 + cs] = u;
  }
}

// V bf16 [B,S,D] -> Vt bf16 [B,D,S]
__global__ __launch_bounds__(256) void k_vt(const u16* __restrict__ V, u16* __restrict__ Vt) {
  __shared__ u16 lt[64][72];
  int b = blockIdx.z;
  int s0 = blockIdx.x * 64, d0 = blockIdx.y * 64;
  int t = threadIdx.x;
#pragma unroll
  for (int i = 0; i < 2; ++i) {
    int lin = t + i * 256;          // chunk of 8
    int r = lin >> 3, c8 = (lin & 7) * 8;
    short8 v = *(const short8*)&V[(b * 2048 + s0 + r) * 2048 + d0 + c8];
    *(short8*)&lt[r][c8] = v;
  }
  __syncthreads();
#pragma unroll
  for (int i = 0; i < 8; ++i) {
    int lin = t + i * 256;
    int rd = lin >> 5, cs = (lin & 31) * 2;
    us2 u = {lt[cs][rd], lt[cs + 1][rd]};
    *(us2*)&Vt[(b * 2048 + d0 + rd) * 2048 + s0 + cs] = u;
  }
}

// RoPE in place on Q (with 1/sqrt(128) scale) and K; interleaved-pair rotation
__global__ __launch_bounds__(256) void k_rope(u16* __restrict__ Qb, u16* __restrict__ Kb,
                                              const float* __restrict__ cos1,
                                              const float* __restrict__ sin1,
                                              const float* __restrict__ cos2,
                                              const float* __restrict__ sin2) {
  u16* T = blockIdx.y ? Kb : Qb;
  const float scale = blockIdx.y ? 1.f : 0.08838834764831843f;
  int tid = blockIdx.x * 256 + threadIdx.x;
  int e = tid * 8;
  int m = e >> 11;
  int n = m & 2047;
  int dh0 = e & 127;
  const float* cr; const float* sr;
  if (n < 1024) { cr = cos1 + n * 128; sr = sin1 + n * 128; }
  else          { cr = cos2 + (n - 1024) * 128; sr = sin2 + (n - 1024) * 128; }
  float4 c0 = *(const float4*)(cr + dh0), c1 = *(const float4*)(cr + dh0 + 4);
  float4 s0 = *(const float4*)(sr + dh0), s1 = *(const float4*)(sr + dh0 + 4);
  short8 xv = *(short8*)(T + e);
  float x0 = bf2f((u16)xv[0]), x1 = bf2f((u16)xv[1]), x2 = bf2f((u16)xv[2]), x3 = bf2f((u16)xv[3]);
  float x4 = bf2f((u16)xv[4]), x5 = bf2f((u16)xv[5]), x6 = bf2f((u16)xv[6]), x7 = bf2f((u16)xv[7]);
  us4 o0 = { f2bf((x0 * c0.x - x1 * s0.x) * scale), f2bf((x1 * c0.x + x0 * s0.x) * scale),
             f2bf((x2 * c0.z - x3 * s0.z) * scale), f2bf((x3 * c0.z + x2 * s0.z) * scale) };
  us4 o1 = { f2bf((x4 * c1.x - x5 * s1.x) * scale), f2bf((x5 * c1.x + x4 * s1.x) * scale),
             f2bf((x6 * c1.z - x7 * s1.z) * scale), f2bf((x7 * c1.z + x6 * s1.z) * scale) };
  *(us4*)(T + e) = o0;
  *(us4*)(T + e + 4) = o1;
}

// ---------------- GEMM core (m97-style, 128x128, BK=64, 4 waves) ----------------

__device__ __forceinline__ void gemm_core(const u16* __restrict__ A,
                                          const u16* __restrict__ Bt,
                                          u16* lA, u16* lB,
                                          f32x4 acc[4][4], int m0, int n0) {
  const int t = threadIdx.x;
  const int lane = t & 63;
  const int lq = lane & 15, lg = lane >> 4;
  const int wr = (t >> 7) & 1, wc = (t >> 6) & 1;
  for (int k0 = 0; k0 < 2048; k0 += 64) {
    __syncthreads();
#pragma unroll
    for (int i = 0; i < 4; ++i) {
      int chunk = i * 256 + t;            // [0,1024): r = chunk/8, c16 = chunk%8
      int r = chunk >> 3, c = chunk & 7;
      GLL16(A + ((m0 + r) * 2048 + k0 + c * 8), lA + chunk * 8);
      GLL16(Bt + ((n0 + r) * 2048 + k0 + c * 8), lB + chunk * 8);
    }
    asm volatile("s_waitcnt vmcnt(0)" ::: "memory");
    __syncthreads();
#pragma unroll
    for (int kc = 0; kc < 2; ++kc) {
      short8 af[4], bf[4];
#pragma unroll
      for (int rf = 0; rf < 4; ++rf)
        af[rf] = *(const short8*)(lA + (wr * 64 + rf * 16 + lq) * 64 + kc * 32 + lg * 8);
#pragma unroll
      for (int cf = 0; cf < 4; ++cf)
        bf[cf] = *(const short8*)(lB + (wc * 64 + cf * 16 + lq) * 64 + kc * 32 + lg * 8);
#pragma unroll
      for (int rf = 0; rf < 4; ++rf)
#pragma unroll
        for (int cf = 0; cf < 4; ++cf)
          acc[rf][cf] = MFMA16x32(af[rf], bf[cf], acc[rf][cf]);
    }
  }
}

struct QKVP {
  const u16* wt[6];      // [type*2 + stream]: q1,q2,k1,k2,v1,v2
  const float* bias[6];
  u16* out[3];           // Q, K, V  (bf16 [B,S,D])
  const u16* xc;
};

__global__ __launch_bounds__(256) void k_gemm_qkv(QKVP p) {
  __shared__ u16 lA[128 * 64];
  __shared__ u16 lB[128 * 64];
  const int m0 = blockIdx.x * 128, n0 = blockIdx.y * 128;
  const int idx = blockIdx.z * 2 + ((m0 >> 10) & 1);
  f32x4 acc[4][4];
  const f32x4 z4 = {0.f, 0.f, 0.f, 0.f};
#pragma unroll
  for (int a = 0; a < 4; ++a)
#pragma unroll
    for (int b = 0; b < 4; ++b) acc[a][b] = z4;
  gemm_core(p.xc, p.wt[idx], lA, lB, acc, m0, n0);
  const float* bias = p.bias[idx];
  u16* out = p.out[blockIdx.z];
  const int lane = threadIdx.x & 63, lq = lane & 15, lg = lane >> 4;
  const int wr = (threadIdx.x >> 7) & 1, wc = (threadIdx.x >> 6) & 1;
#pragma unroll
  for (int cf = 0; cf < 4; ++cf) {
    int col = n0 + wc * 64 + cf * 16 + lq;
    float bv = bias[col];
#pragma unroll
    for (int rf = 0; rf < 4; ++rf) {
      int row0 = m0 + wr * 64 + rf * 16 + lg * 4;
#pragma unroll
      for (int j = 0; j < 4; ++j)
        out[(row0 + j) * 2048 + col] = f2bf(acc[rf][cf][j] + bv);
    }
  }
}

__global__ __launch_bounds__(256) void k_gemm_out(const u16* __restrict__ O,
                                                  const u16* __restrict__ wt0,
                                                  const u16* __restrict__ wt1,
                                                  const float* __restrict__ b0,
                                                  const float* __restrict__ b1,
                                                  float* __restrict__ out) {
  __shared__ u16 lA[128 * 64];
  __shared__ u16 lB[128 * 64];
  const int m0 = blockIdx.x * 128, n0 = blockIdx.y * 128;
  const int stream1 = (m0 >> 10) & 1;
  f32x4 acc[4][4];
  const f32x4 z4 = {0.f, 0.f, 0.f, 0.f};
#pragma unroll
  for (int a = 0; a < 4; ++a)
#pragma unroll
    for (int b = 0; b < 4; ++b) acc[a][b] = z4;
  gemm_core(O, stream1 ? wt1 : wt0, lA, lB, acc, m0, n0);
  const float* bias = stream1 ? b1 : b0;
  const int lane = threadIdx.x & 63, lq = lane & 15, lg = lane >> 4;
  const int wr = (threadIdx.x >> 7) & 1, wc = (threadIdx.x >> 6) & 1;
#pragma unroll
  for (int cf = 0; cf < 4; ++cf) {
    int col = n0 + wc * 64 + cf * 16 + lq;
    float bv = bias[col];
#pragma unroll
    for (int rf = 0; rf < 4; ++rf) {
      int row0 = m0 + wr * 64 + rf * 16 + lg * 4;
#pragma unroll
      for (int j = 0; j < 4; ++j) {
        int row = row0 + j;
        int b = row >> 11, n = row & 2047;
        float* dst = stream1 ? out + 4194304 + (((b << 10) + n - 1024) * 2048 + col)
                             : out + (((b << 10) + n) * 2048 + col);
        *dst = acc[rf][cf][j] + bv;
      }
    }
  }
}

// ---------------- flash attention v2 ----------------
// 4 waves x 32 q-rows = 128 q/block; KVBLK=64; K,V LDS double-buffered via
// global_load_lds with XOR-swizzled source (rule #21); swapped-operand MFMA.
// Q,K bf16 [B,S,D] (RoPE'd, Q pre-scaled); Vt bf16 [B,D,S]; O bf16 [B,S,D]
__global__ __launch_bounds__(256) void k_attn(const u16* __restrict__ Q,
                                              const u16* __restrict__ K,
                                              const u16* __restrict__ Vt,
                                              u16* __restrict__ O) {
  __shared__ __align__(16) u16 kbuf[2][64 * 128];   // [key][dh], row 256B, swizzled
  __shared__ __align__(16) u16 vbuf[2][128 * 64];   // [dh][key], row 128B, swizzled
  __shared__ __align__(16) u16 pbuf[4][16 * 88];    // per-wave P [16 q][64+pad k]
  const int t = threadIdx.x, lane = t & 63, w = t >> 6;
  const int lq = lane & 15, g = lane >> 4;
  // XCD-chunked swizzle: all 16 q-tiles of one (b,h) land on one XCD's L2
  const int id = blockIdx.x;                 // 512 blocks
  const int lgid = (id & 7) * 64 + (id >> 3);
  const int bh = lgid >> 4, qt = lgid & 15;
  const int b = bh >> 4, h = bh & 15;

  // Q fragments in registers: 2 groups of 16 q-rows
  short8 qf[2][4];
#pragma unroll
  for (int u = 0; u < 2; ++u) {
    const u16* Qp = Q + (size_t)(b * 2048 + qt * 128 + w * 32 + u * 16 + lq) * 2048
                    + h * 128 + g * 8;
#pragma unroll
    for (int c = 0; c < 4; ++c) qf[u][c] = *(const short8*)(Qp + c * 32);
  }

  f32x4 oacc[2][8];
  const f32x4 z4 = {0.f, 0.f, 0.f, 0.f};
#pragma unroll
  for (int u = 0; u < 2; ++u)
#pragma unroll
    for (int dc = 0; dc < 8; ++dc) oacc[u][dc] = z4;
  float m_run[2] = {-1e30f, -1e30f}, l_run[2] = {0.f, 0.f};

  const int swz = (lq & 7) << 4;            // read-side XOR (row&7 == lq&7)

  auto STAGE = [&](int bs, int kt) {
#pragma unroll
    for (int ii = 0; ii < 4; ++ii) {
      int i = w * 4 + ii;
      int o = i * 1024 + lane * 16;         // linear LDS byte offset
      {                                      // K tile: row=key (256B rows)
        int row = o >> 8, colb = o & 255;
        int sc = colb ^ ((row & 7) << 4);
        GLL16(K + (size_t)(b * 2048 + kt + row) * 2048 + h * 128 + (sc >> 1),
              (u16*)((char*)kbuf[bs] + o));
      }
      {                                      // V tile: row=dh (128B rows)
        int row = o >> 7, colb = o & 127;
        int sc = colb ^ ((row & 7) << 4);
        GLL16(Vt + (size_t)(b * 2048 + h * 128 + row) * 2048 + kt + (sc >> 1),
              (u16*)((char*)vbuf[bs] + o));
      }
    }
  };

  STAGE(0, 0);
  asm volatile("s_waitcnt vmcnt(0)" ::: "memory");
  __syncthreads();

  for (int tt = 0; tt < 32; ++tt) {
    const int cb = tt & 1;
    if (tt < 31) STAGE(cb ^ 1, (tt + 1) * 64);

    const char* kb = (const char*)kbuf[cb];
    const char* vb = (const char*)vbuf[cb];
    // ---- QK^T: S^T[key][q] for 4 key-groups x 2 q-groups ----
    f32x4 s[2][4];
#pragma unroll
    for (int u = 0; u < 2; ++u)
#pragma unroll
      for (int kg = 0; kg < 4; ++kg) s[u][kg] = z4;
#pragma unroll
    for (int c = 0; c < 4; ++c) {
#pragma unroll
      for (int kg = 0; kg < 4; ++kg) {
        short8 kf = *(const short8*)(kb + (kg * 16 + lq) * 256 + ((c * 64 + g * 16) ^ swz));
        s[0][kg] = MFMA16x32(kf, qf[0][c], s[0][kg]);
        s[1][kg] = MFMA16x32(kf, qf[1][c], s[1][kg]);
      }
    }
    // ---- online softmax per q-group; P -> LDS -> B-operand regs ----
    u16* pw = pbuf[w];
    short8 pb[2][2];
#pragma unroll
    for (int u = 0; u < 2; ++u) {
      float pm = -1e30f;
#pragma unroll
      for (int kg = 0; kg < 4; ++kg)
#pragma unroll
        for (int j = 0; j < 4; ++j) pm = fmaxf(pm, s[u][kg][j]);
      pm = fmaxf(pm, __shfl_xor(pm, 16));
      pm = fmaxf(pm, __shfl_xor(pm, 32));
      const float mnew = fmaxf(m_run[u], pm);
      const float r = __expf(m_run[u] - mnew);
      m_run[u] = mnew;
      float ps = 0.f;
#pragma unroll
      for (int kg = 0; kg < 4; ++kg) {
        float p0 = __expf(s[u][kg][0] - mnew), p1 = __expf(s[u][kg][1] - mnew);
        float p2 = __expf(s[u][kg][2] - mnew), p3 = __expf(s[u][kg][3] - mnew);
        ps += (p0 + p1) + (p2 + p3);
        us4 wv = {f2bf(p0), f2bf(p1), f2bf(p2), f2bf(p3)};
        *(us4*)(pw + lq * 88 + kg * 16 + g * 4) = wv;
      }
      ps += __shfl_xor(ps, 16);
      ps += __shfl_xor(ps, 32);
      l_run[u] = l_run[u] * r + ps;
#pragma unroll
      for (int dc = 0; dc < 8; ++dc) oacc[u][dc] = oacc[u][dc] * r;
      pb[u][0] = *(const short8*)(pw + lq * 88 + g * 8);
      pb[u][1] = *(const short8*)(pw + lq * 88 + 32 + g * 8);
    }
    // ---- PV: O^T[dh][q] ----
#pragma unroll
    for (int kc = 0; kc < 2; ++kc) {
#pragma unroll
      for (int dc = 0; dc < 8; ++dc) {
        short8 vf = *(const short8*)(vb + (dc * 16 + lq) * 128 + ((kc * 64 + g * 16) ^ swz));
        oacc[0][dc] = MFMA16x32(vf, pb[0][kc], oacc[0][dc]);
        oacc[1][dc] = MFMA16x32(vf, pb[1][kc], oacc[1][dc]);
      }
    }
    asm volatile("s_waitcnt vmcnt(0)" ::: "memory");
    __syncthreads();
  }

#pragma unroll
  for (int u = 0; u < 2; ++u) {
    const float inv = 1.f / l_run[u];
    u16* Op = O + (size_t)(b * 2048 + qt * 128 + w * 32 + u * 16 + lq) * 2048
              + h * 128 + g * 4;
#pragma unroll
    for (int dc = 0; dc < 8; ++dc) {
      us4 ov = {f2bf(oacc[u][dc][0] * inv), f2bf(oacc[u][dc][1] * inv),
                f2bf(oacc[u][dc][2] * inv), f2bf(oacc[u][dc][3] * inv)};
      *(us4*)(Op + dc * 16) = ov;
    }
  }
}

// ---------------- host ----------------

extern "C" void kernel_launch(void* const* d_in, const int* in_sizes, int n_in,
                              void* d_out, int out_size, void* d_ws, size_t ws_size,
                              hipStream_t stream) {
  const float* x1   = (const float*)d_in[0];
  const float* x2   = (const float*)d_in[1];
  const float* cos1 = (const float*)d_in[2];
  const float* sin1 = (const float*)d_in[3];
  const float* cos2 = (const float*)d_in[4];
  const float* sin2 = (const float*)d_in[5];
  W8 wp; const float* bias[8];
  for (int i = 0; i < 8; ++i) {
    wp.w[i] = (const float*)d_in[6 + 2 * i];   // wq1,wk1,wv1,wo1,wq2,wk2,wv2,wo2
    bias[i] = (const float*)d_in[7 + 2 * i];   // bq1,bk1,bv1,bo1,bq2,bk2,bv2,bo2
  }
  float* out = (float*)d_out;
  u16* ws = (u16*)d_ws;
  const size_t NX = 8388608;    // B*S*D
  const size_t WSZ = 4194304;   // 2048*2048
  u16* xc = ws;                 // also reused as Vt after QKV GEMM
  u16* wt = ws + NX;
  u16* Qb = wt + 8 * WSZ;
  u16* Kb = Qb + NX;
  u16* Vb = Kb + NX;
  u16* Ob = Vb + NX;
  u16* Vt = xc;
  if (ws_size < (size_t)((Ob + NX) - ws) * sizeof(u16)) return;  // ~151 MB needed

  k_convert_x<<<dim3(4096), dim3(256), 0, stream>>>(x1, x2, xc);
  k_wt<<<dim3(32, 32, 8), dim3(256), 0, stream>>>(wp, wt);

  QKVP qp;
  qp.wt[0] = wt + 0 * WSZ; qp.wt[1] = wt + 4 * WSZ;   // wq1, wq2
  qp.wt[2] = wt + 1 * WSZ; qp.wt[3] = wt + 5 * WSZ;   // wk1, wk2
  qp.wt[4] = wt + 2 * WSZ; qp.wt[5] = wt + 6 * WSZ;   // wv1, wv2
  qp.bias[0] = bias[0]; qp.bias[1] = bias[4];
  qp.bias[2] = bias[1]; qp.bias[3] = bias[5];
  qp.bias[4] = bias[2]; qp.bias[5] = bias[6];
  qp.out[0] = Qb; qp.out[1] = Kb; qp.out[2] = Vb;
  qp.xc = xc;
  k_gemm_qkv<<<dim3(32, 16, 3), dim3(256), 0, stream>>>(qp);

  k_rope<<<dim3(4096, 2), dim3(256), 0, stream>>>(Qb, Kb, cos1, sin1, cos2, sin2);
  k_vt<<<dim3(32, 32, 2), dim3(256), 0, stream>>>(Vb, Vt);
  k_attn<<<dim3(512), dim3(256), 0, stream>>>(Qb, Kb, Vt, Ob);
  k_gemm_out<<<dim3(32, 16), dim3(256), 0, stream>>>(Ob, wt + 3 * WSZ, wt + 7 * WSZ,
                                                     bias[3], bias[7], out);
}